// Round 9
// baseline (391.317 us; speedup 1.0000x reference)
//
#include <hip/hip_runtime.h>
#include <hip/hip_bf16.h>

// Encoder layer. fp32 in/out, bf16 MFMA compute, fp32 accum.
// B=16 S=512 H=768 A=12 DH=64 F=3072.
// Round 19: flash T12 — P kept IN REGISTERS (no lP round-trip).
//   With swapped-operand 32x32 QK^T, lane (l31,khalf) holds its q-row's P at
//   k = s*8 + 4*khalf + r (slot s=0..7, r=0..3), packed to bf16 as pd[s].
//   PV A-frag for kk needs k = kk*16 + khalf*8 + 0..7 = [group0@s | group1@s]
//   with s = 2kk+khalf; own group from pd[s], partner group via
//   __shfl_xor(pd[2kk+1-khalf], 32) (partner evaluates pd[2kk+my_khalf]).
//   Removes per K-tile: 8 ds_write + 4 ds_read_b128 + 1 __syncthreads (P was
//   wave-private; middle barrier only protected lP) + frees 9 KB LDS.
//   Catalog T12: +9% attn for this transform (m214v22).
// r18 learning: QKV de-scatter was neutral; the 84us top dispatch is FFN1 at
// this session's clocks (session clock variance ~15% >> cross-round deltas).
// GEMM line closed (r11-r17): gemm128 2.4-blocks/CU desync is the plateau.
// Fragment algebra (proven r10): row=l31, k=kk*16+khalf*8, phys chunk =
// (kk*2+khalf)^(row&7); D swapped: lane=m, reg g*4+r -> n=8g+4khalf+r.

using bf16_t = __hip_bfloat16;
typedef __bf16 bf16x8 __attribute__((ext_vector_type(8)));
typedef float f32x4 __attribute__((ext_vector_type(4)));
typedef float f32x16 __attribute__((ext_vector_type(16)));

__device__ __forceinline__ float b2f(bf16_t v) { return __bfloat162float(v); }
__device__ __forceinline__ bf16_t f2b(float v) { return __float2bfloat16(v); }
__device__ __forceinline__ ushort f2bu(float v) { bf16_t b = f2b(v); return *(ushort*)&b; }

// async global->LDS 16B copy (dest = wave base + lane*16 by construction)
__device__ __forceinline__ void glds16(const ushort* g, ushort* l) {
    __builtin_amdgcn_global_load_lds(
        (const __attribute__((address_space(1))) unsigned int*)g,
        (__attribute__((address_space(3))) unsigned int*)l, 16, 0, 0);
}

// tanh-form GELU (overflow-safe), |err vs exact| ~1e-3 << 0.102 threshold
__device__ __forceinline__ float gelu_f(float x) {
    float x2 = x * x;
    float y2 = 1.5957691216057308f * x * fmaf(0.044715f, x2, 1.0f);
    float e = __expf(y2);
    float t = 1.f - 2.f / (e + 1.f);
    return 0.5f * x * (1.f + t);
}

// ---------------------------------------------------------------------------
// Prep mega-kernel: 6 weight transposes + bias concat + X cast. One launch.
// ---------------------------------------------------------------------------
__device__ __forceinline__ void tr_tile(const float* __restrict__ in,
                                        bf16_t* __restrict__ out,
                                        int R, int C, int tx, int ty,
                                        float (*t)[65], int tid)
{
    int r0 = ty * 64, c0 = tx * 64;
    int tr = tid >> 6, tc = tid & 63;
#pragma unroll 4
    for (int i = 0; i < 16; ++i) {
        int r = i * 4 + tr;
        t[r][tc] = in[(size_t)(r0 + r) * C + c0 + tc];
    }
    __syncthreads();
#pragma unroll 4
    for (int i = 0; i < 16; ++i) {
        int r = i * 4 + tr;
        out[(size_t)(c0 + r) * R + r0 + tc] = f2b(t[tc][r]);
    }
}

__global__ __launch_bounds__(256) void prep_kernel(
    const float* __restrict__ WQ, const float* __restrict__ WK,
    const float* __restrict__ WV, const float* __restrict__ WO,
    const float* __restrict__ W1, const float* __restrict__ W2,
    const float* __restrict__ bQ, const float* __restrict__ bK,
    const float* __restrict__ bV, const float* __restrict__ X,
    bf16_t* __restrict__ Wqkv, bf16_t* __restrict__ WOt,
    bf16_t* __restrict__ W1t, bf16_t* __restrict__ W2t,
    float* __restrict__ bcat, bf16_t* __restrict__ Xb)
{
    __shared__ float t[64][65];
    const int blk = blockIdx.x, tid = threadIdx.x;
    if (blk < 576) {
        int m = blk / 144, tt = blk % 144;
        const float* in = (m == 0) ? WQ : (m == 1) ? WK : (m == 2) ? WV : WO;
        bf16_t* out = (m == 0) ? Wqkv : (m == 1) ? Wqkv + 589824
                    : (m == 2) ? Wqkv + 1179648 : WOt;
        tr_tile(in, out, 768, 768, tt % 12, tt / 12, t, tid);
    } else if (blk < 1152) {
        int tt = blk - 576;
        tr_tile(W1, W1t, 768, 3072, tt % 48, tt / 48, t, tid);
    } else if (blk < 1728) {
        int tt = blk - 1152;
        tr_tile(W2, W2t, 3072, 768, tt % 12, tt / 12, t, tid);
    } else if (blk == 1728) {
        for (int i = tid; i < 2304; i += 256)
            bcat[i] = (i < 768) ? bQ[i] : (i < 1536) ? bK[i - 768] : bV[i - 1536];
    } else {
        size_t i = ((size_t)(blk - 1729) * 256 + tid) * 8;
        float4 a = *(const float4*)(X + i);
        float4 b = *(const float4*)(X + i + 4);
#pragma unroll
        for (int j = 0; j < 4; ++j) {
            Xb[i + j]     = f2b(((const float*)&a)[j]);
            Xb[i + 4 + j] = f2b(((const float*)&b)[j]);
        }
    }
}

// ---------------------------------------------------------------------------
// vtrans: per-head V transpose. Vb's V-segment per (b,hl) is a contiguous
// [512 s][64 d] row-major matrix at Vb + b*393216 + hl*32768. Output
// Vt[hh][d][s] = transpose. Both sides coalesced; pad 65 -> 2-way (free).
// ---------------------------------------------------------------------------
__global__ __launch_bounds__(256) void vtrans_kernel(
    const bf16_t* __restrict__ Vb, bf16_t* __restrict__ Vt)
{
    __shared__ ushort t[64][65];
    const int hh = blockIdx.x;           // 0..191
    const int sc = blockIdx.y;           // 0..7
    const int b = hh / 12, hl = hh % 12;
    const ushort* in = (const ushort*)Vb + (size_t)b * 393216 + hl * 32768 + sc * 4096;
    ushort* out = (ushort*)Vt + (size_t)hh * 32768 + sc * 64;
    const int tid = threadIdx.x;
    const int tr = tid >> 6, tc = tid & 63;
#pragma unroll 4
    for (int i = 0; i < 16; ++i) {
        int r = i * 4 + tr;
        t[r][tc] = in[r * 64 + tc];
    }
    __syncthreads();
#pragma unroll 4
    for (int i = 0; i < 16; ++i) {
        int d = i * 4 + tr;
        out[(size_t)d * 512 + tc] = t[tc][d];
    }
}

// ---------------------------------------------------------------------------
// NT GEMM, BK=64, swapped-operand mfma_f32_32x32x16_bf16 (round-10 proven).
// Tile 128 x NTILE x 64, 256 thr = 4 waves; wave quadrant 64 x (NTILE/2).
// EPI: 1 bias+GELU->bf16 | 2 bias+res(fp32,ld=ldc)->bf16
//      5 bias+res(bf16,ld=ldc)->fp32 | 6 bias, segmented packed QKV.
// ---------------------------------------------------------------------------
template <int EPI, int NTILE>
__global__ __launch_bounds__(256) void gemm128(
    const bf16_t* __restrict__ A, const bf16_t* __restrict__ Bt,
    const float* __restrict__ bias, const void* __restrict__ res,
    void* __restrict__ Cv, int K, int lda, int ldb, int ldc)
{
    __shared__ ushort lA[128 * 64];
    __shared__ ushort lB[NTILE * 64];
    constexpr int NI = NTILE / 64;           // 32x32 n-subtiles per wave
    const int tid = threadIdx.x;
    const int l = tid & 63, w = tid >> 6;
    const int l31 = l & 31, khalf = l >> 5;  // frag row / k-half
    const int m0 = blockIdx.x * 128, n0 = blockIdx.y * NTILE;

    const int srow = tid >> 3;
    const int sg = (((tid & 7) ^ (srow & 7)) << 3);
    const ushort* gA = (const ushort*)A + (size_t)(m0 + srow) * lda + sg;
    const ushort* gB = (const ushort*)Bt + (size_t)(n0 + srow) * ldb + sg;
    ushort* dA = lA + tid * 8;
    ushort* dB = lB + tid * 8;

    f32x16 acc[2][NI] = {};
    const int arow = (w & 1) * 64;
    const int brow = (w >> 1) * (NTILE / 2);

    for (int k0 = 0; k0 < K; k0 += 64) {
        __syncthreads();
        glds16(gA + k0,                      dA);
        glds16(gA + k0 + (size_t)32 * lda,   dA + 2048);
        glds16(gA + k0 + (size_t)64 * lda,   dA + 4096);
        glds16(gA + k0 + (size_t)96 * lda,   dA + 6144);
        glds16(gB + k0,                      dB);
        glds16(gB + k0 + (size_t)32 * ldb,   dB + 2048);
        if constexpr (NTILE == 128) {
            glds16(gB + k0 + (size_t)64 * ldb, dB + 4096);
            glds16(gB + k0 + (size_t)96 * ldb, dB + 6144);
        }
        __syncthreads();
#pragma unroll
        for (int kk = 0; kk < 4; ++kk) {
            const int pc = (((kk * 2 + khalf) ^ (l31 & 7)) << 3);
            bf16x8 bfr[NI];
#pragma unroll
            for (int ni = 0; ni < NI; ++ni)
                bfr[ni] = *(const bf16x8*)&lB[(brow + ni * 32 + l31) * 64 + pc];
#pragma unroll
            for (int mi = 0; mi < 2; ++mi) {
                bf16x8 afr = *(const bf16x8*)&lA[(arow + mi * 32 + l31) * 64 + pc];
#pragma unroll
                for (int ni = 0; ni < NI; ++ni)   // SWAPPED: D lane=m, regs=n
                    acc[mi][ni] = __builtin_amdgcn_mfma_f32_32x32x16_bf16(bfr[ni], afr, acc[mi][ni], 0, 0, 0);
            }
        }
    }

    // Epilogue: m = arow + mi*32 + l31; reg g*4+r -> n = ni*32 + 8g + 4*khalf + r
#pragma unroll
    for (int mi = 0; mi < 2; ++mi) {
        int m = m0 + arow + mi * 32 + l31;
#pragma unroll
        for (int ni = 0; ni < NI; ++ni) {
#pragma unroll
            for (int g = 0; g < 4; ++g) {
                int nb = n0 + brow + ni * 32 + 8 * g + 4 * khalf;  // 4 consecutive n
                float4 bv4 = *(const float4*)&bias[nb];
                float v[4];
#pragma unroll
                for (int r = 0; r < 4; ++r) v[r] = acc[mi][ni][g * 4 + r] + ((const float*)&bv4)[r];
                if constexpr (EPI == 1) {
#pragma unroll
                    for (int r = 0; r < 4; ++r) v[r] = gelu_f(v[r]);
                } else if constexpr (EPI == 2) {
                    float4 r4 = *(const float4*)&((const float*)res)[(size_t)m * ldc + nb];
#pragma unroll
                    for (int r = 0; r < 4; ++r) v[r] += ((const float*)&r4)[r];
                } else if constexpr (EPI == 5) {
                    ushort4 rb = *(const ushort4*)&((const ushort*)res)[(size_t)m * ldc + nb];
#pragma unroll
                    for (int r = 0; r < 4; ++r) v[r] += b2f(*(const bf16_t*)&((const ushort*)&rb)[r]);
                }
                if constexpr (EPI == 5) {
                    *(float4*)&((float*)Cv)[(size_t)m * ldc + nb] = make_float4(v[0], v[1], v[2], v[3]);
                } else {
                    ushort4 st;
                    st.x = f2bu(v[0]); st.y = f2bu(v[1]); st.z = f2bu(v[2]); st.w = f2bu(v[3]);
                    if constexpr (EPI == 6) {
                        int seg = n0 / 768;      // block-uniform (768 % NTILE == 0)
                        int nloc = (n0 % 768) + brow + ni * 32 + 8 * g + 4 * khalf;
                        bf16_t* Cseg = (bf16_t*)Cv + (size_t)seg * 6291456;
                        *(ushort4*)&((ushort*)Cseg)[(size_t)m * 768 + nloc] = st;
                    } else {
                        *(ushort4*)&((ushort*)Cv)[(size_t)m * ldc + nb] = st;
                    }
                }
            }
        }
    }
}

// ---------------------------------------------------------------------------
// Flash attention, Q-tile 128, swapped-operand 32x32x16 MFMA, in-register P
// (T12). One block = (q-tile 128, head); wave w owns q rows w*32 + l31; the
// (l31, l31+32) lane pair holds the two khalf column-subsets of one q-row.
// Per K-tile: stage K,V -> sync -> QK^T -> softmax -> pack P to pd[8] ->
// PV with shfl_xor(32) frag exchange -> sync. 2 barriers/tile, LDS 16 KB.
// ---------------------------------------------------------------------------
__global__ __launch_bounds__(256) void flash_kernel(
    const bf16_t* __restrict__ Q, const bf16_t* __restrict__ Kx,
    const bf16_t* __restrict__ Vt, const int* __restrict__ mask,
    bf16_t* __restrict__ Z)
{
    __shared__ ushort lK[64 * 64];
    __shared__ ushort lV[64 * 64];

    const int h = blockIdx.y;
    const int q0 = blockIdx.x * 128;
    const ushort* Qh = (const ushort*)Q + (size_t)h * 32768;
    const ushort* Kh = (const ushort*)Kx + (size_t)h * 32768;
    const ushort* Vh = (const ushort*)Vt + (size_t)h * 32768;   // [64][512]
    const int* mk = mask + (h / 12) * 512;
    ushort* Zh = (ushort*)Z + (size_t)h * 32768;

    const int tid = threadIdx.x;
    const int l = tid & 63, w = tid >> 6;
    const int l31 = l & 31, khalf = l >> 5;

    // Q A-frags from global (row-major): row = qrow, k = kk*16 + khalf*8
    const int qrow = q0 + w * 32 + l31;
    bf16x8 qfr[4];
#pragma unroll
    for (int kk = 0; kk < 4; ++kk)
        qfr[kk] = *(const bf16x8*)(Qh + (size_t)qrow * 64 + kk * 16 + khalf * 8);

    const int c8p = tid & 7;
    const int kr0 = tid >> 3;
    float m_i = -1e30f, l_i = 0.f;
    f32x16 o4[2] = {};

    for (int kt = 0; kt < 8; ++kt) {
#pragma unroll
        for (int p = 0; p < 2; ++p) {
            int row = kr0 + p * 32;
            int c8l = c8p ^ (row & 7);
            glds16(Kh + (size_t)(kt * 64 + row) * 64 + c8l * 8, lK + (p * 256 + tid) * 8);
            glds16(Vh + (size_t)row * 512 + kt * 64 + c8l * 8, lV + (p * 256 + tid) * 8);
        }
        __syncthreads();

        // QK^T: s4[nt] covers k = nt*32 + (8g + 4khalf + r)
        f32x16 s4[2] = {};
#pragma unroll
        for (int kk = 0; kk < 4; ++kk) {
            const int pc = (((kk * 2 + khalf) ^ (l31 & 7)) << 3);
#pragma unroll
            for (int nt = 0; nt < 2; ++nt) {
                bf16x8 kfr = *(const bf16x8*)&lK[(nt * 32 + l31) * 64 + pc];
                s4[nt] = __builtin_amdgcn_mfma_f32_32x32x16_bf16(kfr, qfr[kk], s4[nt], 0, 0, 0);
            }
        }

        // mask + scale + row-max (in place in s4)
        float rm = -1e30f;
#pragma unroll
        for (int nt = 0; nt < 2; ++nt) {
            int4 mg[4];
#pragma unroll
            for (int g = 0; g < 4; ++g)
                mg[g] = *(const int4*)&mk[kt * 64 + nt * 32 + 8 * g + 4 * khalf];
#pragma unroll
            for (int g = 0; g < 4; ++g)
#pragma unroll
                for (int r = 0; r < 4; ++r) {
                    float v = (((const int*)&mg[g])[r] == 0) ? -1e30f : s4[nt][g * 4 + r] * 0.125f;
                    s4[nt][g * 4 + r] = v;
                    rm = fmaxf(rm, v);
                }
        }
        rm = fmaxf(rm, __shfl_xor(rm, 32));   // combine khalf pair -> full row
        float mn = fmaxf(m_i, rm);
        float al = __expf(m_i - mn);
        float rs = 0.f;
#pragma unroll
        for (int nt = 0; nt < 2; ++nt)
#pragma unroll
            for (int j = 0; j < 16; ++j) {
                float e = __expf(s4[nt][j] - mn);
                s4[nt][j] = e;
                rs += e;
            }
        rs += __shfl_xor(rs, 32);
        l_i = l_i * al + rs;
        m_i = mn;
#pragma unroll
        for (int dt = 0; dt < 2; ++dt)
#pragma unroll
            for (int j = 0; j < 16; ++j) o4[dt][j] *= al;

        // P -> bf16 in-register: pd[s] packs s4[s>>2][(s&3)*4 + 0..3];
        // slot s holds k = s*8 + 4*khalf + r for this lane's khalf group.
        uint2 pd[8];
#pragma unroll
        for (int s = 0; s < 8; ++s) {
            int nt = s >> 2, g = s & 3;
            pd[s].x = (unsigned)f2bu(s4[nt][g * 4 + 0]) | ((unsigned)f2bu(s4[nt][g * 4 + 1]) << 16);
            pd[s].y = (unsigned)f2bu(s4[nt][g * 4 + 2]) | ((unsigned)f2bu(s4[nt][g * 4 + 3]) << 16);
        }

        // PV. A-frag for kk = P[q][kk*16 + khalf*8 + 0..7] = [group0@s|group1@s],
        // s = 2kk+khalf; own group = pd[s]; partner group via shfl_xor(32) of
        // pd[2kk+1-khalf] (partner evaluates pd[2kk+my_khalf] -> I receive it,
        // it receives pd[2kk+1-my_khalf] = its needed slot). Verified at
        // (l31,khalf=0/1, kk=1): lanes exchange exactly slot-2/slot-3 pairs.
#pragma unroll
        for (int kk = 0; kk < 4; ++kk) {
            uint2 snd = pd[2 * kk + 1 - khalf];
            uint2 ex;
            ex.x = (unsigned)__shfl_xor((int)snd.x, 32);
            ex.y = (unsigned)__shfl_xor((int)snd.y, 32);
            uint2 ow = pd[2 * kk + khalf];
            union { unsigned u[4]; bf16x8 v; } fu;
            if (khalf == 0) { fu.u[0] = ow.x; fu.u[1] = ow.y; fu.u[2] = ex.x; fu.u[3] = ex.y; }
            else            { fu.u[0] = ex.x; fu.u[1] = ex.y; fu.u[2] = ow.x; fu.u[3] = ow.y; }
            const int pc = (((kk * 2 + khalf) ^ (l31 & 7)) << 3);
#pragma unroll
            for (int dt = 0; dt < 2; ++dt) {
                bf16x8 vfr = *(const bf16x8*)&lV[(dt * 32 + l31) * 64 + pc];
                o4[dt] = __builtin_amdgcn_mfma_f32_32x32x16_bf16(vfr, fu.v, o4[dt], 0, 0, 0);
            }
        }
        __syncthreads();
    }

    float inv = 1.f / l_i;
#pragma unroll
    for (int dt = 0; dt < 2; ++dt)
#pragma unroll
        for (int g = 0; g < 4; ++g) {
            ushort4 st;
            st.x = f2bu(o4[dt][g * 4 + 0] * inv); st.y = f2bu(o4[dt][g * 4 + 1] * inv);
            st.z = f2bu(o4[dt][g * 4 + 2] * inv); st.w = f2bu(o4[dt][g * 4 + 3] * inv);
            *(ushort4*)&Zh[(size_t)qrow * 64 + dt * 32 + 8 * g + 4 * khalf] = st;
        }
}

// ---------------------------------------------------------------------------
// LayerNorm over H=768, one block per row, fp32 stats. In-place safe.
// ---------------------------------------------------------------------------
__device__ __forceinline__ float to_f(float v)  { return v; }
__device__ __forceinline__ float to_f(bf16_t v) { return b2f(v); }
__device__ __forceinline__ void from_f(float& d, float v)  { d = v; }
__device__ __forceinline__ void from_f(bf16_t& d, float v) { d = f2b(v); }

template <typename TI, typename TO>
__global__ __launch_bounds__(256) void layernorm_kernel(
    const TI* __restrict__ X, const float* __restrict__ w,
    const float* __restrict__ b, TO* __restrict__ out)
{
    const TI* x = X + (size_t)blockIdx.x * 768;
    TO* o = out + (size_t)blockIdx.x * 768;
    int t = threadIdx.x;
    float v[3];
    float s = 0.f, sq = 0.f;
#pragma unroll
    for (int i = 0; i < 3; ++i) {
        v[i] = to_f(x[t + i * 256]);
        s += v[i]; sq += v[i] * v[i];
    }
#pragma unroll
    for (int off = 32; off; off >>= 1) { s += __shfl_xor(s, off); sq += __shfl_xor(sq, off); }
    __shared__ float s1[4], s2[4];
    int wave = t >> 6, lane = t & 63;
    if (lane == 0) { s1[wave] = s; s2[wave] = sq; }
    __syncthreads();
    s  = s1[0] + s1[1] + s1[2] + s1[3];
    sq = s2[0] + s2[1] + s2[2] + s2[3];
    float mu  = s * (1.f / 768.f);
    float var = sq * (1.f / 768.f) - mu * mu;
    float rs  = rsqrtf(var + 1e-5f);
#pragma unroll
    for (int i = 0; i < 3; ++i)
        from_f(o[t + i * 256], (v[i] - mu) * rs * w[t + i * 256] + b[t + i * 256]);
}

// ---------------------------------------------------------------------------
extern "C" void kernel_launch(void* const* d_in, const int* in_sizes, int n_in,
                              void* d_out, int out_size, void* d_ws, size_t ws_size,
                              hipStream_t stream)
{
    const float* X    = (const float*)d_in[0];
    const int*   mask = (const int*)  d_in[1];
    const float* WQ   = (const float*)d_in[2];
    const float* bQ   = (const float*)d_in[3];
    const float* WK   = (const float*)d_in[4];
    const float* bK   = (const float*)d_in[5];
    const float* WV   = (const float*)d_in[6];
    const float* bV   = (const float*)d_in[7];
    const float* WO   = (const float*)d_in[8];
    const float* bO   = (const float*)d_in[9];
    const float* ln1w = (const float*)d_in[10];
    const float* ln1b = (const float*)d_in[11];
    const float* W1   = (const float*)d_in[12];
    const float* b1   = (const float*)d_in[13];
    const float* W2   = (const float*)d_in[14];
    const float* b2   = (const float*)d_in[15];
    const float* ln2w = (const float*)d_in[16];
    const float* ln2b = (const float*)d_in[17];
    float* out = (float*)d_out;

    // ---- workspace (bf16 elems; total 38,539,776 = 77.1 MB) ----
    bf16_t* ws   = (bf16_t*)d_ws;
    bf16_t* Wqkv = ws;                        // [2304][768] (WQt|WKt|WVt)
    bf16_t* WOt  = Wqkv + 1769472;            // [768][768]
    bf16_t* W1t  = WOt + 589824;              // [3072][768]
    bf16_t* W2t  = W1t + 2359296;             // [768][3072]
    float*  bcat = (float*)(W2t + 2359296);   // fp32[2304] (= 4608 bf16)
    bf16_t* Qb   = W2t + 2359296 + 4608;      // packed [8192][768]; Q,K,V consecutive (EPI 6)
    bf16_t* Kb   = Qb + 6291456;
    bf16_t* Vb   = Kb + 6291456;              // packed V (clean writes); vtrans -> Vt
    bf16_t* Xb   = Vb + 6291456;              // bf16 X (dead after QKV; Y1 alias)
    bf16_t* Vt   = Xb + 6291456;              // per-head V^T [192][64][512], from vtrans
    // aliases (dead-before-write):
    bf16_t* Zb = Qb;   // flash writes Z in-place over Q
    bf16_t* Y1 = Xb;   // O-proj out (Xb dead after QKV gemm)
    bf16_t* X1 = Qb;   // LN1 out (Qb/Z dead after O-proj)
    bf16_t* Hb = Kb;   // FFN mid [8192][3072] = Kb+Vb+Xb+Vt exactly

    // ---- 1. prep ----
    prep_kernel<<<4801, 256, 0, stream>>>(WQ, WK, WV, WO, W1, W2, bQ, bK, bV, X,
                                          Wqkv, WOt, W1t, W2t, bcat, Xb);

    // ---- 2. fused QKV projection -> packed Qb|Kb|Vb ----
    gemm128<6, 128><<<dim3(64, 18), 256, 0, stream>>>(Xb, Wqkv, bcat, nullptr, Qb,
                                                      768, 768, 768, 768);

    // ---- 2b. per-head V transpose Vb -> Vt ----
    vtrans_kernel<<<dim3(192, 8), 256, 0, stream>>>(Vb, Vt);

    // ---- 3. flash attention (in-register P), Z in-place over Q ----
    flash_kernel<<<dim3(4, 192), 256, 0, stream>>>(Qb, Kb, Vt, mask, Zb);

    // ---- 4. O-projection + fp32 residual -> Y1, LN1 -> X1 ----
    gemm128<2, 64><<<dim3(64, 12), 256, 0, stream>>>(Zb, WOt, bO, X, Y1,
                                                     768, 768, 768, 768);
    layernorm_kernel<bf16_t, bf16_t><<<8192, 256, 0, stream>>>(Y1, ln1w, ln1b, X1);

    // ---- 5. FFN ----
    gemm128<1, 128><<<dim3(64, 24), 256, 0, stream>>>(X1, W1t, b1, nullptr, Hb,
                                                      768, 768, 768, 3072);
    gemm128<5, 64><<<dim3(64, 12), 256, 0, stream>>>(Hb, W2t, b2, X1, out,
                                                     3072, 3072, 3072, 768);
    layernorm_kernel<float, float><<<8192, 256, 0, stream>>>(out, ln2w, ln2b, out);
}

// Round 10
// 357.101 us; speedup vs baseline: 1.0958x; 1.0958x over previous
//
#include <hip/hip_runtime.h>
#include <hip/hip_bf16.h>

// Encoder layer. fp32 in/out, bf16 MFMA compute, fp32 accum.
// B=16 S=512 H=768 A=12 DH=64 F=3072.
// Round 20: REVERT to round-18 config (best measured: 359.2 us).
//   r19's T12 (in-register P + shfl_xor exchange) regressed flash 
//   ~50->68.5 us: shfl (= ds_bpermute) sits INSIDE the softmax->PV
//   dependency chain (cannot hoist — input is just-computed), vs the LDS
//   round-trip whose ds_read_b128s the compiler issues early and counts
//   down with lgkmcnt while MFMAs run. MfmaUtil 6.9 / VALUBusy 27 = latency
//   chain, not bandwidth. T12 is regime-gated (catalog rule #23); on this
//   4-wave structure it is NEGATIVE. Flash restored to r16 32x32 version.
// State of play: GEMM line closed (r11-r17: five structures converge at
// ~520 TF; wide tiles lose residency, deep schedules don't beat 2.4-blk/CU
// desync). Flash 32x32 + vtrans + packed QKV = best known config.
// Fragment algebra (proven r10): row=l31, k=kk*16+khalf*8, phys chunk =
// (kk*2+khalf)^(row&7); D swapped: lane=m, reg g*4+r -> n=8g+4khalf+r.

using bf16_t = __hip_bfloat16;
typedef __bf16 bf16x8 __attribute__((ext_vector_type(8)));
typedef float f32x4 __attribute__((ext_vector_type(4)));
typedef float f32x16 __attribute__((ext_vector_type(16)));

__device__ __forceinline__ float b2f(bf16_t v) { return __bfloat162float(v); }
__device__ __forceinline__ bf16_t f2b(float v) { return __float2bfloat16(v); }
__device__ __forceinline__ ushort f2bu(float v) { bf16_t b = f2b(v); return *(ushort*)&b; }

// async global->LDS 16B copy (dest = wave base + lane*16 by construction)
__device__ __forceinline__ void glds16(const ushort* g, ushort* l) {
    __builtin_amdgcn_global_load_lds(
        (const __attribute__((address_space(1))) unsigned int*)g,
        (__attribute__((address_space(3))) unsigned int*)l, 16, 0, 0);
}

// tanh-form GELU (overflow-safe), |err vs exact| ~1e-3 << 0.102 threshold
__device__ __forceinline__ float gelu_f(float x) {
    float x2 = x * x;
    float y2 = 1.5957691216057308f * x * fmaf(0.044715f, x2, 1.0f);
    float e = __expf(y2);
    float t = 1.f - 2.f / (e + 1.f);
    return 0.5f * x * (1.f + t);
}

// ---------------------------------------------------------------------------
// Prep mega-kernel: 6 weight transposes + bias concat + X cast. One launch.
// ---------------------------------------------------------------------------
__device__ __forceinline__ void tr_tile(const float* __restrict__ in,
                                        bf16_t* __restrict__ out,
                                        int R, int C, int tx, int ty,
                                        float (*t)[65], int tid)
{
    int r0 = ty * 64, c0 = tx * 64;
    int tr = tid >> 6, tc = tid & 63;
#pragma unroll 4
    for (int i = 0; i < 16; ++i) {
        int r = i * 4 + tr;
        t[r][tc] = in[(size_t)(r0 + r) * C + c0 + tc];
    }
    __syncthreads();
#pragma unroll 4
    for (int i = 0; i < 16; ++i) {
        int r = i * 4 + tr;
        out[(size_t)(c0 + r) * R + r0 + tc] = f2b(t[tc][r]);
    }
}

__global__ __launch_bounds__(256) void prep_kernel(
    const float* __restrict__ WQ, const float* __restrict__ WK,
    const float* __restrict__ WV, const float* __restrict__ WO,
    const float* __restrict__ W1, const float* __restrict__ W2,
    const float* __restrict__ bQ, const float* __restrict__ bK,
    const float* __restrict__ bV, const float* __restrict__ X,
    bf16_t* __restrict__ Wqkv, bf16_t* __restrict__ WOt,
    bf16_t* __restrict__ W1t, bf16_t* __restrict__ W2t,
    float* __restrict__ bcat, bf16_t* __restrict__ Xb)
{
    __shared__ float t[64][65];
    const int blk = blockIdx.x, tid = threadIdx.x;
    if (blk < 576) {
        int m = blk / 144, tt = blk % 144;
        const float* in = (m == 0) ? WQ : (m == 1) ? WK : (m == 2) ? WV : WO;
        bf16_t* out = (m == 0) ? Wqkv : (m == 1) ? Wqkv + 589824
                    : (m == 2) ? Wqkv + 1179648 : WOt;
        tr_tile(in, out, 768, 768, tt % 12, tt / 12, t, tid);
    } else if (blk < 1152) {
        int tt = blk - 576;
        tr_tile(W1, W1t, 768, 3072, tt % 48, tt / 48, t, tid);
    } else if (blk < 1728) {
        int tt = blk - 1152;
        tr_tile(W2, W2t, 3072, 768, tt % 12, tt / 12, t, tid);
    } else if (blk == 1728) {
        for (int i = tid; i < 2304; i += 256)
            bcat[i] = (i < 768) ? bQ[i] : (i < 1536) ? bK[i - 768] : bV[i - 1536];
    } else {
        size_t i = ((size_t)(blk - 1729) * 256 + tid) * 8;
        float4 a = *(const float4*)(X + i);
        float4 b = *(const float4*)(X + i + 4);
#pragma unroll
        for (int j = 0; j < 4; ++j) {
            Xb[i + j]     = f2b(((const float*)&a)[j]);
            Xb[i + 4 + j] = f2b(((const float*)&b)[j]);
        }
    }
}

// ---------------------------------------------------------------------------
// vtrans: per-head V transpose. Vb's V-segment per (b,hl) is a contiguous
// [512 s][64 d] row-major matrix at Vb + b*393216 + hl*32768. Output
// Vt[hh][d][s] = transpose. Both sides coalesced; pad 65 -> 2-way (free).
// ---------------------------------------------------------------------------
__global__ __launch_bounds__(256) void vtrans_kernel(
    const bf16_t* __restrict__ Vb, bf16_t* __restrict__ Vt)
{
    __shared__ ushort t[64][65];
    const int hh = blockIdx.x;           // 0..191
    const int sc = blockIdx.y;           // 0..7
    const int b = hh / 12, hl = hh % 12;
    const ushort* in = (const ushort*)Vb + (size_t)b * 393216 + hl * 32768 + sc * 4096;
    ushort* out = (ushort*)Vt + (size_t)hh * 32768 + sc * 64;
    const int tid = threadIdx.x;
    const int tr = tid >> 6, tc = tid & 63;
#pragma unroll 4
    for (int i = 0; i < 16; ++i) {
        int r = i * 4 + tr;
        t[r][tc] = in[r * 64 + tc];
    }
    __syncthreads();
#pragma unroll 4
    for (int i = 0; i < 16; ++i) {
        int d = i * 4 + tr;
        out[(size_t)d * 512 + tc] = t[tc][d];
    }
}

// ---------------------------------------------------------------------------
// NT GEMM, BK=64, swapped-operand mfma_f32_32x32x16_bf16 (round-10 proven).
// Tile 128 x NTILE x 64, 256 thr = 4 waves; wave quadrant 64 x (NTILE/2).
// EPI: 1 bias+GELU->bf16 | 2 bias+res(fp32,ld=ldc)->bf16
//      5 bias+res(bf16,ld=ldc)->fp32 | 6 bias, segmented packed QKV.
// ---------------------------------------------------------------------------
template <int EPI, int NTILE>
__global__ __launch_bounds__(256) void gemm128(
    const bf16_t* __restrict__ A, const bf16_t* __restrict__ Bt,
    const float* __restrict__ bias, const void* __restrict__ res,
    void* __restrict__ Cv, int K, int lda, int ldb, int ldc)
{
    __shared__ ushort lA[128 * 64];
    __shared__ ushort lB[NTILE * 64];
    constexpr int NI = NTILE / 64;           // 32x32 n-subtiles per wave
    const int tid = threadIdx.x;
    const int l = tid & 63, w = tid >> 6;
    const int l31 = l & 31, khalf = l >> 5;  // frag row / k-half
    const int m0 = blockIdx.x * 128, n0 = blockIdx.y * NTILE;

    const int srow = tid >> 3;
    const int sg = (((tid & 7) ^ (srow & 7)) << 3);
    const ushort* gA = (const ushort*)A + (size_t)(m0 + srow) * lda + sg;
    const ushort* gB = (const ushort*)Bt + (size_t)(n0 + srow) * ldb + sg;
    ushort* dA = lA + tid * 8;
    ushort* dB = lB + tid * 8;

    f32x16 acc[2][NI] = {};
    const int arow = (w & 1) * 64;
    const int brow = (w >> 1) * (NTILE / 2);

    for (int k0 = 0; k0 < K; k0 += 64) {
        __syncthreads();
        glds16(gA + k0,                      dA);
        glds16(gA + k0 + (size_t)32 * lda,   dA + 2048);
        glds16(gA + k0 + (size_t)64 * lda,   dA + 4096);
        glds16(gA + k0 + (size_t)96 * lda,   dA + 6144);
        glds16(gB + k0,                      dB);
        glds16(gB + k0 + (size_t)32 * ldb,   dB + 2048);
        if constexpr (NTILE == 128) {
            glds16(gB + k0 + (size_t)64 * ldb, dB + 4096);
            glds16(gB + k0 + (size_t)96 * ldb, dB + 6144);
        }
        __syncthreads();
#pragma unroll
        for (int kk = 0; kk < 4; ++kk) {
            const int pc = (((kk * 2 + khalf) ^ (l31 & 7)) << 3);
            bf16x8 bfr[NI];
#pragma unroll
            for (int ni = 0; ni < NI; ++ni)
                bfr[ni] = *(const bf16x8*)&lB[(brow + ni * 32 + l31) * 64 + pc];
#pragma unroll
            for (int mi = 0; mi < 2; ++mi) {
                bf16x8 afr = *(const bf16x8*)&lA[(arow + mi * 32 + l31) * 64 + pc];
#pragma unroll
                for (int ni = 0; ni < NI; ++ni)   // SWAPPED: D lane=m, regs=n
                    acc[mi][ni] = __builtin_amdgcn_mfma_f32_32x32x16_bf16(bfr[ni], afr, acc[mi][ni], 0, 0, 0);
            }
        }
    }

    // Epilogue: m = arow + mi*32 + l31; reg g*4+r -> n = ni*32 + 8g + 4*khalf + r
#pragma unroll
    for (int mi = 0; mi < 2; ++mi) {
        int m = m0 + arow + mi * 32 + l31;
#pragma unroll
        for (int ni = 0; ni < NI; ++ni) {
#pragma unroll
            for (int g = 0; g < 4; ++g) {
                int nb = n0 + brow + ni * 32 + 8 * g + 4 * khalf;  // 4 consecutive n
                float4 bv4 = *(const float4*)&bias[nb];
                float v[4];
#pragma unroll
                for (int r = 0; r < 4; ++r) v[r] = acc[mi][ni][g * 4 + r] + ((const float*)&bv4)[r];
                if constexpr (EPI == 1) {
#pragma unroll
                    for (int r = 0; r < 4; ++r) v[r] = gelu_f(v[r]);
                } else if constexpr (EPI == 2) {
                    float4 r4 = *(const float4*)&((const float*)res)[(size_t)m * ldc + nb];
#pragma unroll
                    for (int r = 0; r < 4; ++r) v[r] += ((const float*)&r4)[r];
                } else if constexpr (EPI == 5) {
                    ushort4 rb = *(const ushort4*)&((const ushort*)res)[(size_t)m * ldc + nb];
#pragma unroll
                    for (int r = 0; r < 4; ++r) v[r] += b2f(*(const bf16_t*)&((const ushort*)&rb)[r]);
                }
                if constexpr (EPI == 5) {
                    *(float4*)&((float*)Cv)[(size_t)m * ldc + nb] = make_float4(v[0], v[1], v[2], v[3]);
                } else {
                    ushort4 st;
                    st.x = f2bu(v[0]); st.y = f2bu(v[1]); st.z = f2bu(v[2]); st.w = f2bu(v[3]);
                    if constexpr (EPI == 6) {
                        int seg = n0 / 768;      // block-uniform (768 % NTILE == 0)
                        int nloc = (n0 % 768) + brow + ni * 32 + 8 * g + 4 * khalf;
                        bf16_t* Cseg = (bf16_t*)Cv + (size_t)seg * 6291456;
                        *(ushort4*)&((ushort*)Cseg)[(size_t)m * 768 + nloc] = st;
                    } else {
                        *(ushort4*)&((ushort*)Cv)[(size_t)m * ldc + nb] = st;
                    }
                }
            }
        }
    }
}

// ---------------------------------------------------------------------------
// Flash attention, Q-tile 128, swapped-operand 32x32x16 MFMA (round-16
// verified; P through LDS — the compiler front-loads the ds_read_b128s and
// counts lgkmcnt down across the MFMA chain, which beats the shfl variant).
// One block = (q-tile 128, head); wave w owns q rows w*32 + l31.
// ---------------------------------------------------------------------------
__global__ __launch_bounds__(256) void flash_kernel(
    const bf16_t* __restrict__ Q, const bf16_t* __restrict__ Kx,
    const bf16_t* __restrict__ Vt, const int* __restrict__ mask,
    bf16_t* __restrict__ Z)
{
    __shared__ ushort lK[64 * 64];
    __shared__ ushort lV[64 * 64];
    __shared__ ushort lP[128 * 72];

    const int h = blockIdx.y;
    const int q0 = blockIdx.x * 128;
    const ushort* Qh = (const ushort*)Q + (size_t)h * 32768;
    const ushort* Kh = (const ushort*)Kx + (size_t)h * 32768;
    const ushort* Vh = (const ushort*)Vt + (size_t)h * 32768;   // [64][512]
    const int* mk = mask + (h / 12) * 512;
    ushort* Zh = (ushort*)Z + (size_t)h * 32768;

    const int tid = threadIdx.x;
    const int l = tid & 63, w = tid >> 6;
    const int l31 = l & 31, khalf = l >> 5;

    // Q A-frags from global (row-major): row = qrow, k = kk*16 + khalf*8
    const int qrow = q0 + w * 32 + l31;
    bf16x8 qfr[4];
#pragma unroll
    for (int kk = 0; kk < 4; ++kk)
        qfr[kk] = *(const bf16x8*)(Qh + (size_t)qrow * 64 + kk * 16 + khalf * 8);

    const int c8p = tid & 7;
    const int kr0 = tid >> 3;
    float m_i = -1e30f, l_i = 0.f;
    f32x16 o4[2] = {};
    const int prow = (w * 32 + l31) * 72;

    for (int kt = 0; kt < 8; ++kt) {
#pragma unroll
        for (int p = 0; p < 2; ++p) {
            int row = kr0 + p * 32;
            int c8l = c8p ^ (row & 7);
            glds16(Kh + (size_t)(kt * 64 + row) * 64 + c8l * 8, lK + (p * 256 + tid) * 8);
            glds16(Vh + (size_t)row * 512 + kt * 64 + c8l * 8, lV + (p * 256 + tid) * 8);
        }
        __syncthreads();

        // QK^T: s4[nt] covers k = nt*32 + (8g + 4khalf + r)
        f32x16 s4[2] = {};
#pragma unroll
        for (int kk = 0; kk < 4; ++kk) {
            const int pc = (((kk * 2 + khalf) ^ (l31 & 7)) << 3);
#pragma unroll
            for (int nt = 0; nt < 2; ++nt) {
                bf16x8 kfr = *(const bf16x8*)&lK[(nt * 32 + l31) * 64 + pc];
                s4[nt] = __builtin_amdgcn_mfma_f32_32x32x16_bf16(kfr, qfr[kk], s4[nt], 0, 0, 0);
            }
        }

        // mask + scale + row-max (in place in s4)
        float rm = -1e30f;
#pragma unroll
        for (int nt = 0; nt < 2; ++nt) {
            int4 mg[4];
#pragma unroll
            for (int g = 0; g < 4; ++g)
                mg[g] = *(const int4*)&mk[kt * 64 + nt * 32 + 8 * g + 4 * khalf];
#pragma unroll
            for (int g = 0; g < 4; ++g)
#pragma unroll
                for (int r = 0; r < 4; ++r) {
                    float v = (((const int*)&mg[g])[r] == 0) ? -1e30f : s4[nt][g * 4 + r] * 0.125f;
                    s4[nt][g * 4 + r] = v;
                    rm = fmaxf(rm, v);
                }
        }
        rm = fmaxf(rm, __shfl_xor(rm, 32));   // combine khalf pair -> full row
        float mn = fmaxf(m_i, rm);
        float al = __expf(m_i - mn);
        float rs = 0.f;
#pragma unroll
        for (int nt = 0; nt < 2; ++nt)
#pragma unroll
            for (int j = 0; j < 16; ++j) {
                float e = __expf(s4[nt][j] - mn);
                s4[nt][j] = e;
                rs += e;
            }
        rs += __shfl_xor(rs, 32);
        l_i = l_i * al + rs;
        m_i = mn;
#pragma unroll
        for (int dt = 0; dt < 2; ++dt)
#pragma unroll
            for (int j = 0; j < 16; ++j) o4[dt][j] *= al;

        // P -> LDS: row = qrow-local, col k = nt*32 + 8g + 4khalf (+r)
#pragma unroll
        for (int nt = 0; nt < 2; ++nt)
#pragma unroll
            for (int g = 0; g < 4; ++g) {
                ushort4 st;
                st.x = f2bu(s4[nt][g * 4 + 0]); st.y = f2bu(s4[nt][g * 4 + 1]);
                st.z = f2bu(s4[nt][g * 4 + 2]); st.w = f2bu(s4[nt][g * 4 + 3]);
                *(ushort4*)&lP[prow + nt * 32 + 8 * g + 4 * khalf] = st;
            }
        __syncthreads();

        // PV: o4[dt] covers d = dt*32 + (8g + 4khalf + r)
#pragma unroll
        for (int kk = 0; kk < 4; ++kk) {
            bf16x8 pafr = *(const bf16x8*)&lP[prow + kk * 16 + khalf * 8];
            const int pc = (((kk * 2 + khalf) ^ (l31 & 7)) << 3);
#pragma unroll
            for (int dt = 0; dt < 2; ++dt) {
                bf16x8 vfr = *(const bf16x8*)&lV[(dt * 32 + l31) * 64 + pc];
                o4[dt] = __builtin_amdgcn_mfma_f32_32x32x16_bf16(vfr, pafr, o4[dt], 0, 0, 0);
            }
        }
        __syncthreads();
    }

    float inv = 1.f / l_i;
#pragma unroll
    for (int dt = 0; dt < 2; ++dt)
#pragma unroll
        for (int g = 0; g < 4; ++g) {
            ushort4 st;
            st.x = f2bu(o4[dt][g * 4 + 0] * inv); st.y = f2bu(o4[dt][g * 4 + 1] * inv);
            st.z = f2bu(o4[dt][g * 4 + 2] * inv); st.w = f2bu(o4[dt][g * 4 + 3] * inv);
            *(ushort4*)&Zh[(size_t)qrow * 64 + dt * 32 + 8 * g + 4 * khalf] = st;
        }
}

// ---------------------------------------------------------------------------
// LayerNorm over H=768, one block per row, fp32 stats. In-place safe.
// ---------------------------------------------------------------------------
__device__ __forceinline__ float to_f(float v)  { return v; }
__device__ __forceinline__ float to_f(bf16_t v) { return b2f(v); }
__device__ __forceinline__ void from_f(float& d, float v)  { d = v; }
__device__ __forceinline__ void from_f(bf16_t& d, float v) { d = f2b(v); }

template <typename TI, typename TO>
__global__ __launch_bounds__(256) void layernorm_kernel(
    const TI* __restrict__ X, const float* __restrict__ w,
    const float* __restrict__ b, TO* __restrict__ out)
{
    const TI* x = X + (size_t)blockIdx.x * 768;
    TO* o = out + (size_t)blockIdx.x * 768;
    int t = threadIdx.x;
    float v[3];
    float s = 0.f, sq = 0.f;
#pragma unroll
    for (int i = 0; i < 3; ++i) {
        v[i] = to_f(x[t + i * 256]);
        s += v[i]; sq += v[i] * v[i];
    }
#pragma unroll
    for (int off = 32; off; off >>= 1) { s += __shfl_xor(s, off); sq += __shfl_xor(sq, off); }
    __shared__ float s1[4], s2[4];
    int wave = t >> 6, lane = t & 63;
    if (lane == 0) { s1[wave] = s; s2[wave] = sq; }
    __syncthreads();
    s  = s1[0] + s1[1] + s1[2] + s1[3];
    sq = s2[0] + s2[1] + s2[2] + s2[3];
    float mu  = s * (1.f / 768.f);
    float var = sq * (1.f / 768.f) - mu * mu;
    float rs  = rsqrtf(var + 1e-5f);
#pragma unroll
    for (int i = 0; i < 3; ++i)
        from_f(o[t + i * 256], (v[i] - mu) * rs * w[t + i * 256] + b[t + i * 256]);
}

// ---------------------------------------------------------------------------
extern "C" void kernel_launch(void* const* d_in, const int* in_sizes, int n_in,
                              void* d_out, int out_size, void* d_ws, size_t ws_size,
                              hipStream_t stream)
{
    const float* X    = (const float*)d_in[0];
    const int*   mask = (const int*)  d_in[1];
    const float* WQ   = (const float*)d_in[2];
    const float* bQ   = (const float*)d_in[3];
    const float* WK   = (const float*)d_in[4];
    const float* bK   = (const float*)d_in[5];
    const float* WV   = (const float*)d_in[6];
    const float* bV   = (const float*)d_in[7];
    const float* WO   = (const float*)d_in[8];
    const float* bO   = (const float*)d_in[9];
    const float* ln1w = (const float*)d_in[10];
    const float* ln1b = (const float*)d_in[11];
    const float* W1   = (const float*)d_in[12];
    const float* b1   = (const float*)d_in[13];
    const float* W2   = (const float*)d_in[14];
    const float* b2   = (const float*)d_in[15];
    const float* ln2w = (const float*)d_in[16];
    const float* ln2b = (const float*)d_in[17];
    float* out = (float*)d_out;

    // ---- workspace (bf16 elems; total 38,539,776 = 77.1 MB) ----
    bf16_t* ws   = (bf16_t*)d_ws;
    bf16_t* Wqkv = ws;                        // [2304][768] (WQt|WKt|WVt)
    bf16_t* WOt  = Wqkv + 1769472;            // [768][768]
    bf16_t* W1t  = WOt + 589824;              // [3072][768]
    bf16_t* W2t  = W1t + 2359296;             // [768][3072]
    float*  bcat = (float*)(W2t + 2359296);   // fp32[2304] (= 4608 bf16)
    bf16_t* Qb   = W2t + 2359296 + 4608;      // packed [8192][768]; Q,K,V consecutive (EPI 6)
    bf16_t* Kb   = Qb + 6291456;
    bf16_t* Vb   = Kb + 6291456;              // packed V (clean writes); vtrans -> Vt
    bf16_t* Xb   = Vb + 6291456;              // bf16 X (dead after QKV; Y1 alias)
    bf16_t* Vt   = Xb + 6291456;              // per-head V^T [192][64][512], from vtrans
    // aliases (dead-before-write):
    bf16_t* Zb = Qb;   // flash writes Z in-place over Q
    bf16_t* Y1 = Xb;   // O-proj out (Xb dead after QKV gemm)
    bf16_t* X1 = Qb;   // LN1 out (Qb/Z dead after O-proj)
    bf16_t* Hb = Kb;   // FFN mid [8192][3072] = Kb+Vb+Xb+Vt exactly

    // ---- 1. prep ----
    prep_kernel<<<4801, 256, 0, stream>>>(WQ, WK, WV, WO, W1, W2, bQ, bK, bV, X,
                                          Wqkv, WOt, W1t, W2t, bcat, Xb);

    // ---- 2. fused QKV projection -> packed Qb|Kb|Vb ----
    gemm128<6, 128><<<dim3(64, 18), 256, 0, stream>>>(Xb, Wqkv, bcat, nullptr, Qb,
                                                      768, 768, 768, 768);

    // ---- 2b. per-head V transpose Vb -> Vt ----
    vtrans_kernel<<<dim3(192, 8), 256, 0, stream>>>(Vb, Vt);

    // ---- 3. flash attention (Q-tile 128, 32x32 MFMA), Z in-place over Q ----
    flash_kernel<<<dim3(4, 192), 256, 0, stream>>>(Qb, Kb, Vt, mask, Zb);

    // ---- 4. O-projection + fp32 residual -> Y1, LN1 -> X1 ----
    gemm128<2, 64><<<dim3(64, 12), 256, 0, stream>>>(Zb, WOt, bO, X, Y1,
                                                     768, 768, 768, 768);
    layernorm_kernel<bf16_t, bf16_t><<<8192, 256, 0, stream>>>(Y1, ln1w, ln1b, X1);

    // ---- 5. FFN ----
    gemm128<1, 128><<<dim3(64, 24), 256, 0, stream>>>(X1, W1t, b1, nullptr, Hb,
                                                      768, 768, 768, 3072);
    gemm128<5, 64><<<dim3(64, 12), 256, 0, stream>>>(Hb, W2t, b2, X1, out,
                                                     3072, 3072, 3072, 768);
    layernorm_kernel<float, float><<<8192, 256, 0, stream>>>(out, ln2w, ln2b, out);
}